// Round 5
// baseline (468.844 us; speedup 1.0000x reference)
//
#include <hip/hip_runtime.h>
#include <math.h>

typedef unsigned short ushort_t;
typedef unsigned int uint_t;
typedef short short8 __attribute__((ext_vector_type(8)));
typedef float float4a __attribute__((ext_vector_type(4)));
typedef uint_t uint4a __attribute__((ext_vector_type(4)));
typedef uint_t uint2a __attribute__((ext_vector_type(2)));

#define B_SZ 4
#define S_SZ 2048
#define E_SZ 1024
#define H_SZ 16
#define HD_SZ 64

#if __has_builtin(__builtin_amdgcn_exp2f)
#define EXP2F(x) __builtin_amdgcn_exp2f(x)
#else
#define EXP2F(x) exp2f(x)
#endif

// ---- helpers ----
__device__ __forceinline__ ushort_t f2bf(float f) {
    uint_t u = __builtin_bit_cast(uint_t, f);
    u = (u + 0x7fff + ((u >> 16) & 1)) >> 16;
    return (ushort_t)u;
}
// pack 2 fp32 -> 2 bf16 (round half-up) in one v_perm_b32
__device__ __forceinline__ uint_t pk_bf16(float a, float b) {
    uint_t ua = __builtin_bit_cast(uint_t, a) + 0x8000u;
    uint_t ub = __builtin_bit_cast(uint_t, b) + 0x8000u;
#if __has_builtin(__builtin_amdgcn_perm)
    return __builtin_amdgcn_perm(ub, ua, 0x07060302u);
#else
    return (ua >> 16) | (ub & 0xffff0000u);
#endif
}
__device__ __forceinline__ void async_copy16(const void* g, void* l) {
    __builtin_amdgcn_global_load_lds(
        (const __attribute__((address_space(1))) void*)g,
        (__attribute__((address_space(3))) void*)l, 16, 0, 0);
}

// ---- kernel 1: transpose 4 fp32 weight matrices (E x E) -> bf16 ----
__global__ __launch_bounds__(256) void transpose4(
    const float* __restrict__ W0, const float* __restrict__ W1,
    const float* __restrict__ W2, const float* __restrict__ W3,
    ushort_t* __restrict__ out)
{
    const float* src;
    switch (blockIdx.z) {
        case 0: src = W0; break;
        case 1: src = W1; break;
        case 2: src = W2; break;
        default: src = W3; break;
    }
    ushort_t* dst = out + (size_t)blockIdx.z * (E_SZ * E_SZ);
    __shared__ ushort_t t[32][33];
    int x = blockIdx.x * 32 + threadIdx.x;
    int y0 = blockIdx.y * 32;
    for (int i = threadIdx.y; i < 32; i += 8)
        t[i][threadIdx.x] = f2bf(src[(size_t)(y0 + i) * E_SZ + x]);
    __syncthreads();
    int yy = blockIdx.x * 32;
    int xx = y0 + threadIdx.x;
    for (int i = threadIdx.y; i < 32; i += 8)
        dst[(size_t)(yy + i) * E_SZ + xx] = t[threadIdx.x][i];
}

// ---- kernel 1b: bulk fp32 -> bf16 convert of query/key/value ----
__global__ __launch_bounds__(256) void cvt3(
    const float* __restrict__ s0, const float* __restrict__ s1,
    const float* __restrict__ s2, ushort_t* __restrict__ d0,
    ushort_t* __restrict__ d1, ushort_t* __restrict__ d2)
{
    const float* s; ushort_t* d;
    switch (blockIdx.y) {
        case 0: s = s0; d = d0; break;
        case 1: s = s1; d = d1; break;
        default: s = s2; d = d2; break;
    }
    size_t i = ((size_t)blockIdx.x * 256 + threadIdx.x) * 8;
    float4a u0 = *(const float4a*)(s + i);
    float4a u1 = *(const float4a*)(s + i + 4);
    uint4a w = (uint4a){pk_bf16(u0[0], u0[1]), pk_bf16(u0[2], u0[3]),
                        pk_bf16(u1[0], u1[1]), pk_bf16(u1[2], u1[3])};
    *(uint4a*)(d + i) = w;
}

// ---- GEMM core: Y[m,n] = sum_k X[m,k] * Wt[n,k] + bias[n] ----
// (round-4 version, PASSED at 458 us total: proj3 dropped out of top-5)
// 128x128 tile, BK=32, 4-slot LDS ring (64 KB) with COUNTED vmcnt:
// prefetch 3 K-steps ahead; steady state waits only vmcnt(12).
template<bool OUTF32>
__device__ __forceinline__ void gemm_body(
    const ushort_t* X, const ushort_t* Wt, const float* bias,
    void* Yv, int mode, int tileM, int tileN)
{
    __shared__ __align__(16) ushort_t As[4][4096];   // 8 KB per slot
    __shared__ __align__(16) ushort_t Bs[4][4096];   // 8 KB per slot
    const int tid = threadIdx.x;
    const int lane = tid & 63;
    const int quad = lane >> 4;
    const int l15 = lane & 15;
    const int wid = tid >> 6;
    const int wm = (wid >> 1) * 64;
    const int wn = (wid & 1) * 64;

    float4a acc[4][4];
    #pragma unroll
    for (int i = 0; i < 4; i++)
        #pragma unroll
        for (int j = 0; j < 4; j++)
            acc[i][j] = (float4a){0.f, 0.f, 0.f, 0.f};

    const ushort_t* pA0 = X  + (size_t)(tileM + (tid & 127)) * E_SZ + (tid >> 7) * 8;
    const ushort_t* pA1 = X  + (size_t)(tileM + (tid & 127)) * E_SZ + ((tid >> 7) + 2) * 8;
    const ushort_t* pB0 = Wt + (size_t)(tileN + (tid & 127)) * E_SZ + (tid >> 7) * 8;
    const ushort_t* pB1 = Wt + (size_t)(tileN + (tid & 127)) * E_SZ + ((tid >> 7) + 2) * 8;
    const int d0 = tid * 8;
    const int d1 = (256 + tid) * 8;

#define STAGE(SLOT) do { \
    async_copy16(pA0, &As[SLOT][d0]); \
    async_copy16(pA1, &As[SLOT][d1]); \
    async_copy16(pB0, &Bs[SLOT][d0]); \
    async_copy16(pB1, &Bs[SLOT][d1]); \
    pA0 += 32; pA1 += 32; pB0 += 32; pB1 += 32; } while (0)

    STAGE(0); STAGE(1); STAGE(2);

#define KTILE(SLOT, DOSTAGE, VMS) do { \
    asm volatile("s_waitcnt lgkmcnt(0)" ::: "memory"); \
    __builtin_amdgcn_s_barrier(); \
    asm volatile("" ::: "memory"); \
    if (DOSTAGE) STAGE(((SLOT) + 3) & 3); \
    asm volatile("s_waitcnt vmcnt(" #VMS ")" ::: "memory"); \
    __builtin_amdgcn_s_barrier(); \
    asm volatile("" ::: "memory"); \
    { \
        short8 a[4], b[4]; \
        _Pragma("unroll") \
        for (int mt = 0; mt < 4; mt++) \
            a[mt] = *(const short8*)&As[SLOT][quad * 1024 + (wm + mt * 16 + l15) * 8]; \
        _Pragma("unroll") \
        for (int nt = 0; nt < 4; nt++) \
            b[nt] = *(const short8*)&Bs[SLOT][quad * 1024 + (wn + nt * 16 + l15) * 8]; \
        __builtin_amdgcn_s_setprio(1); \
        _Pragma("unroll") \
        for (int mt = 0; mt < 4; mt++) \
            _Pragma("unroll") \
            for (int nt = 0; nt < 4; nt++) \
                acc[mt][nt] = __builtin_amdgcn_mfma_f32_16x16x32_bf16( \
                    a[mt], b[nt], acc[mt][nt], 0, 0, 0); \
        __builtin_amdgcn_s_setprio(0); \
    } } while (0)

    #pragma unroll 1
    for (int j = 0; j < 28; j += 4) {
        KTILE(0, true, 12);
        KTILE(1, true, 12);
        KTILE(2, true, 12);
        KTILE(3, true, 12);
    }
    KTILE(0, true, 12);
    KTILE(1, false, 8);
    KTILE(2, false, 4);
    KTILE(3, false, 0);
#undef KTILE
#undef STAGE

    #pragma unroll
    for (int nt = 0; nt < 4; nt++) {
        int n = tileN + wn + nt * 16 + l15;
        float bv = bias[n];
        #pragma unroll
        for (int mt = 0; mt < 4; mt++) {
            #pragma unroll
            for (int r = 0; r < 4; r++) {
                int m = tileM + wm + mt * 16 + quad * 4 + r;
                float v = acc[mt][nt][r] + bv;
                if constexpr (OUTF32) {
                    ((float*)Yv)[(size_t)m * E_SZ + n] = v;
                } else {
                    ushort_t* Y = (ushort_t*)Yv;
                    if (mode == 0) {
                        Y[(size_t)m * E_SZ + n] = f2bf(v);
                    } else {
                        int bb = m >> 11, s = m & 2047;
                        Y[((size_t)(bb * E_SZ + n)) * S_SZ + s] = f2bf(v);
                    }
                }
            }
        }
    }
}

// fused Q/K/V projections: z selects input/weight/bias/output.
__global__ __launch_bounds__(256, 2) void proj3(
    const ushort_t* __restrict__ x0, const ushort_t* __restrict__ x1,
    const ushort_t* __restrict__ x2, const ushort_t* __restrict__ Wt,
    const float* __restrict__ b0, const float* __restrict__ b1,
    const float* __restrict__ b2, ushort_t* __restrict__ y0,
    ushort_t* __restrict__ y1, ushort_t* __restrict__ y2)
{
    const ushort_t* X; const float* bias; ushort_t* Y; int mode = 0;
    switch (blockIdx.z) {
        case 0: X = x0; bias = b0; Y = y0; break;
        case 1: X = x1; bias = b1; Y = y1; break;
        default: X = x2; bias = b2; Y = y2; mode = 1; break;
    }
    gemm_body<false>(X, Wt + (size_t)blockIdx.z * E_SZ * E_SZ, bias, Y, mode,
                     blockIdx.y * 128, blockIdx.x * 128);
}

// final output projection: bf16 X -> fp32 Y
__global__ __launch_bounds__(256, 2) void gemm_out(
    const ushort_t* __restrict__ X, const ushort_t* __restrict__ Wt,
    const float* __restrict__ bias, float* __restrict__ Y)
{
    gemm_body<true>(X, Wt, bias, Y, 0, blockIdx.y * 128, blockIdx.x * 128);
}

// ---- kernel 3: flash attention (round-10: 40 KB LDS, per-kk P-slice) ----
// Round-4 PMC: dur 140us, VALUBusy 51%, MfmaUtil 21%, Occupancy 19.6%
// (2 blocks/CU, LDS-limited at 64 KB), BANK_CONFLICT 1.05e7.  Changes:
//  * P round-trip is now per-kk 32-kidx slices through an 8 KB buffer
//    [128][32] (chunk ^= row&3 swizzle; write b64 4/bank-even, read b128
//    8/bank-even => conflict-free), replacing the 32 KB [128][128] P^T.
//    LDS 64->40 KB => 4 blocks/CU.  Same-wave write->read is safe (LDS
//    pipe is in-order per wave; rows are wave-private).
//  * Q staged in a prologue (aliases Vt region), removing the kt==0 case.
//  * defer-max (T13, THR=44 raw = 8 in exp2 domain): skip alpha/rescale
//    when the running max doesn't grow; P bounded by 2^8, bf16-safe.
//  * rmax via max3 chains; setprio(1) around MFMA clusters (T5).
__global__ __launch_bounds__(256) void attn(
    const ushort_t* __restrict__ Q, const ushort_t* __restrict__ K,
    const ushort_t* __restrict__ V, ushort_t* __restrict__ ctx)
{
    __shared__ __align__(16) ushort_t smem[20480];   // 40 KB
    ushort_t* Ks = smem;                 // [g(8)][row(128)][8]  16 KB
    ushort_t* Vt = smem + 8192;          // swizzled [d(64)][c(128)] 16 KB
    ushort_t* Ps = smem + 16384;         // [row(128)][32] swizzled  8 KB
    ushort_t* Qs = smem + 8192;          // prologue alias over Vt

    const int tid = threadIdx.x;
    const int lane = tid & 63;
    const int quad = lane >> 4;
    const int l15 = lane & 15;
    const int wid = tid >> 6;
    const int qt = blockIdx.x;              // 0..15
    const int bh = blockIdx.y;              // 0..63
    const int b = bh >> 4, h = bh & 15;
    const int s0 = qt * 128;
    const int wq = wid * 32;
    const float CE = 0.18033688011f;        // 0.125 * log2(e)

    // ---- prologue: stage Q, pull qf fragments, release the region ----
    for (int p = 0; p < 4; p++) {
        int L = p * 256 + tid;
        int g = L >> 7, r = L & 127;
        const ushort_t* src = Q + ((size_t)(b * S_SZ + s0 + r)) * E_SZ + h * HD_SZ + g * 8;
        async_copy16(src, &Qs[L * 8]);
    }
    __syncthreads();                        // drains vmcnt: Q in LDS
    short8 qf[2][2];
    for (int ks = 0; ks < 2; ks++)
        for (int nt = 0; nt < 2; nt++)
            qf[ks][nt] = *(const short8*)&Qs[(ks * 4 + quad) * 1024 + (wq + nt * 16 + l15) * 8];
    __syncthreads();                        // all qf reads done before Vt staging

    float4a st[8][2];       // S^T acc: mt over kidx(8 x16), nt over q(2 x16)
    float4a o[4][2];        // O^T acc: mt over d(4 x16), nt over q(2 x16)
    for (int mt = 0; mt < 4; mt++)
        for (int nt = 0; nt < 2; nt++)
            o[mt][nt] = (float4a){0.f, 0.f, 0.f, 0.f};
    float mrow[2] = {-1e30f, -1e30f};   // raw-score units
    float lrow[2] = {0.f, 0.f};

    for (int kt = 0; kt < 16; kt++) {
        // stage K tile (async, lane-consecutive 16B)
        for (int p = 0; p < 4; p++) {
            int L = p * 256 + tid;
            int g = L >> 7, r = L & 127;
            const ushort_t* src = K + ((size_t)(b * S_SZ + kt * 128 + r)) * E_SZ + h * HD_SZ + g * 8;
            async_copy16(src, &Ks[L * 8]);
        }
        // stage V^T tile (swizzled rows of 128)
        for (int p = 0; p < 4; p++) {
            int c = p * 256 + tid;
            int d = c >> 4, cc = c & 15;
            const ushort_t* src = V + ((size_t)(b * E_SZ + h * HD_SZ + d)) * S_SZ + kt * 128 + cc * 8;
            short8 val = *(const short8*)src;
            *(short8*)&Vt[d * 128 + ((cc ^ (d & 7)) << 3)] = val;
        }
        __syncthreads();

        // S^T[kidx][q] = sum_d K[kidx][d] * Q[q][d]
        for (int mt = 0; mt < 8; mt++)
            for (int nt = 0; nt < 2; nt++)
                st[mt][nt] = (float4a){0.f, 0.f, 0.f, 0.f};
        __builtin_amdgcn_s_setprio(1);
        for (int ks = 0; ks < 2; ks++) {
            for (int mt = 0; mt < 8; mt++) {
                short8 kf = *(const short8*)&Ks[(ks * 4 + quad) * 1024 + (mt * 16 + l15) * 8];
                for (int nt = 0; nt < 2; nt++)
                    st[mt][nt] = __builtin_amdgcn_mfma_f32_16x16x32_bf16(
                        kf, qf[ks][nt], st[mt][nt], 0, 0, 0);
            }
        }
        __builtin_amdgcn_s_setprio(0);

        // row max via max3 chains, cross-quad reduce
        float rmax[2] = {-1e30f, -1e30f};
        for (int mt = 0; mt < 8; mt++)
            for (int nt = 0; nt < 2; nt++) {
                rmax[nt] = fmaxf(fmaxf(rmax[nt], st[mt][nt][0]), st[mt][nt][1]);
                rmax[nt] = fmaxf(fmaxf(rmax[nt], st[mt][nt][2]), st[mt][nt][3]);
            }
        for (int nt = 0; nt < 2; nt++) {
            rmax[nt] = fmaxf(rmax[nt], __shfl_xor(rmax[nt], 16));
            rmax[nt] = fmaxf(rmax[nt], __shfl_xor(rmax[nt], 32));
        }
        // defer-max: only rescale when the running max grew by > 44 raw
        // (=8 in exp2 domain; P bounded by 2^8, bf16-safe)
        float alpha[2] = {1.f, 1.f};
        int grew = !__all((rmax[0] - mrow[0] <= 44.0f) &&
                          (rmax[1] - mrow[1] <= 44.0f));
        if (grew) {
            float nm0 = fmaxf(mrow[0], rmax[0]);
            float nm1 = fmaxf(mrow[1], rmax[1]);
            alpha[0] = EXP2F((mrow[0] - nm0) * CE);
            alpha[1] = EXP2F((mrow[1] - nm1) * CE);
            mrow[0] = nm0; mrow[1] = nm1;
            for (int mt = 0; mt < 4; mt++)
                for (int nt = 0; nt < 2; nt++)
                    for (int r = 0; r < 4; r++)
                        o[mt][nt][r] *= alpha[nt];
        }
        float mc[2] = {mrow[0] * CE, mrow[1] * CE};
        float rsum[2] = {0.f, 0.f};

        // per 32-kidx slice: exp -> Ps write -> pb read -> PV MFMA.
        // Ps rows are wave-private; same-wave LDS ops are in-order.
        for (int kk = 0; kk < 4; kk++) {
            for (int mtL = 0; mtL < 2; mtL++) {
                int mt = kk * 2 + mtL;
                for (int nt = 0; nt < 2; nt++) {
                    float e0 = EXP2F(fmaf(st[mt][nt][0], CE, -mc[nt]));
                    float e1 = EXP2F(fmaf(st[mt][nt][1], CE, -mc[nt]));
                    float e2 = EXP2F(fmaf(st[mt][nt][2], CE, -mc[nt]));
                    float e3 = EXP2F(fmaf(st[mt][nt][3], CE, -mc[nt]));
                    rsum[nt] += (e0 + e1) + (e2 + e3);
                    uint2a pp = (uint2a){pk_bf16(e0, e1), pk_bf16(e2, e3)};
                    int row = wq + nt * 16 + l15;
                    int ch = (mtL * 2 + (quad >> 1)) ^ (row & 3);
                    *(uint2a*)&Ps[row * 32 + ch * 8 + (quad & 1) * 4] = pp;
                }
            }
            int swzV = ((kk * 4 + quad) ^ (l15 & 7)) << 3;
            short8 a[4], pb[2];
            for (int mt = 0; mt < 4; mt++)
                a[mt] = *(const short8*)&Vt[(mt * 16 + l15) * 128 + swzV];
            for (int nt = 0; nt < 2; nt++) {
                int row = wq + nt * 16 + l15;
                pb[nt] = *(const short8*)&Ps[row * 32 + ((quad ^ (row & 3)) << 3)];
            }
            __builtin_amdgcn_s_setprio(1);
            for (int mt = 0; mt < 4; mt++)
                for (int nt = 0; nt < 2; nt++)
                    o[mt][nt] = __builtin_amdgcn_mfma_f32_16x16x32_bf16(
                        a[mt], pb[nt], o[mt][nt], 0, 0, 0);
            __builtin_amdgcn_s_setprio(0);
        }
        for (int nt = 0; nt < 2; nt++) {
            rsum[nt] += __shfl_xor(rsum[nt], 16);
            rsum[nt] += __shfl_xor(rsum[nt], 32);
            lrow[nt] = lrow[nt] * alpha[nt] + rsum[nt];
        }
        __syncthreads();
    }

    // epilogue: ctx[b, s, h*64+d] = O^T[d][q] / l[q]   (8B packed stores)
    for (int nt = 0; nt < 2; nt++) {
        float inv = 1.f / lrow[nt];
        int s = s0 + wq + nt * 16 + l15;
        size_t base = ((size_t)(b * S_SZ + s)) * E_SZ + h * HD_SZ;
        for (int mt = 0; mt < 4; mt++) {
            int d = mt * 16 + quad * 4;
            uint2a w = (uint2a){pk_bf16(o[mt][nt][0] * inv, o[mt][nt][1] * inv),
                                pk_bf16(o[mt][nt][2] * inv, o[mt][nt][3] * inv)};
            *(uint2a*)&ctx[base + d] = w;
        }
    }
}

extern "C" void kernel_launch(void* const* d_in, const int* in_sizes, int n_in,
                              void* d_out, int out_size, void* d_ws, size_t ws_size,
                              hipStream_t stream) {
    const float* q_in = (const float*)d_in[0];
    const float* k_in = (const float*)d_in[1];
    const float* v_in = (const float*)d_in[2];
    const float* Wq = (const float*)d_in[3];
    const float* bq = (const float*)d_in[4];
    const float* Wk = (const float*)d_in[5];
    const float* bk = (const float*)d_in[6];
    const float* Wv = (const float*)d_in[7];
    const float* bv = (const float*)d_in[8];
    const float* Wo = (const float*)d_in[9];
    const float* bo = (const float*)d_in[10];

    ushort_t* ws = (ushort_t*)d_ws;
    const size_t WMAT = (size_t)E_SZ * E_SZ;           // 1M elements
    const size_t TEN = (size_t)B_SZ * S_SZ * E_SZ;     // 8M elements
    ushort_t* Wt = ws;                 // 4 transposed bf16 weights (8 MB)
    ushort_t* qb = ws + 4 * WMAT;      // bf16 copies of inputs
    ushort_t* kb = qb + TEN;
    ushort_t* vb = kb + TEN;
    ushort_t* qp = vb + TEN;           // projected Q/K/V
    ushort_t* kp = qp + TEN;
    ushort_t* vp = kp + TEN;           // stored [B, E, S]
    ushort_t* cx = qb;                 // ctx aliases qb (dead after proj3)

    transpose4<<<dim3(32, 32, 4), dim3(32, 8), 0, stream>>>(Wq, Wk, Wv, Wo, Wt);
    cvt3<<<dim3(4096, 3), 256, 0, stream>>>(q_in, k_in, v_in, qb, kb, vb);
    proj3<<<dim3(8, 64, 3), 256, 0, stream>>>(qb, kb, vb, Wt, bq, bk, bv, qp, kp, vp);
    attn<<<dim3(16, 64), 256, 0, stream>>>(qp, kp, vp, cx);
    gemm_out<<<dim3(8, 64), 256, 0, stream>>>(cx, Wt + 3 * WMAT, bo, (float*)d_out);
}

// Round 6
// 461.517 us; speedup vs baseline: 1.0159x; 1.0159x over previous
//
#include <hip/hip_runtime.h>
#include <math.h>

typedef unsigned short ushort_t;
typedef unsigned int uint_t;
typedef short short8 __attribute__((ext_vector_type(8)));
typedef float float4a __attribute__((ext_vector_type(4)));
typedef uint_t uint4a __attribute__((ext_vector_type(4)));
typedef uint_t uint2a __attribute__((ext_vector_type(2)));

#define B_SZ 4
#define S_SZ 2048
#define E_SZ 1024
#define H_SZ 16
#define HD_SZ 64

#if __has_builtin(__builtin_amdgcn_exp2f)
#define EXP2F(x) __builtin_amdgcn_exp2f(x)
#else
#define EXP2F(x) exp2f(x)
#endif

// ---- helpers ----
__device__ __forceinline__ ushort_t f2bf(float f) {
    uint_t u = __builtin_bit_cast(uint_t, f);
    u = (u + 0x7fff + ((u >> 16) & 1)) >> 16;
    return (ushort_t)u;
}
// pack 2 fp32 -> 2 bf16 (round half-up) in one v_perm_b32
__device__ __forceinline__ uint_t pk_bf16(float a, float b) {
    uint_t ua = __builtin_bit_cast(uint_t, a) + 0x8000u;
    uint_t ub = __builtin_bit_cast(uint_t, b) + 0x8000u;
#if __has_builtin(__builtin_amdgcn_perm)
    return __builtin_amdgcn_perm(ub, ua, 0x07060302u);
#else
    return (ua >> 16) | (ub & 0xffff0000u);
#endif
}
__device__ __forceinline__ void async_copy16(const void* g, void* l) {
    __builtin_amdgcn_global_load_lds(
        (const __attribute__((address_space(1))) void*)g,
        (__attribute__((address_space(3))) void*)l, 16, 0, 0);
}

// ---- kernel 1: transpose 4 fp32 weight matrices (E x E) -> bf16 ----
__global__ __launch_bounds__(256) void transpose4(
    const float* __restrict__ W0, const float* __restrict__ W1,
    const float* __restrict__ W2, const float* __restrict__ W3,
    ushort_t* __restrict__ out)
{
    const float* src;
    switch (blockIdx.z) {
        case 0: src = W0; break;
        case 1: src = W1; break;
        case 2: src = W2; break;
        default: src = W3; break;
    }
    ushort_t* dst = out + (size_t)blockIdx.z * (E_SZ * E_SZ);
    __shared__ ushort_t t[32][33];
    int x = blockIdx.x * 32 + threadIdx.x;
    int y0 = blockIdx.y * 32;
    for (int i = threadIdx.y; i < 32; i += 8)
        t[i][threadIdx.x] = f2bf(src[(size_t)(y0 + i) * E_SZ + x]);
    __syncthreads();
    int yy = blockIdx.x * 32;
    int xx = y0 + threadIdx.x;
    for (int i = threadIdx.y; i < 32; i += 8)
        dst[(size_t)(yy + i) * E_SZ + xx] = t[threadIdx.x][i];
}

// ---- kernel 1b: bulk fp32 -> bf16 convert of query/key/value ----
__global__ __launch_bounds__(256) void cvt3(
    const float* __restrict__ s0, const float* __restrict__ s1,
    const float* __restrict__ s2, ushort_t* __restrict__ d0,
    ushort_t* __restrict__ d1, ushort_t* __restrict__ d2)
{
    const float* s; ushort_t* d;
    switch (blockIdx.y) {
        case 0: s = s0; d = d0; break;
        case 1: s = s1; d = d1; break;
        default: s = s2; d = d2; break;
    }
    size_t i = ((size_t)blockIdx.x * 256 + threadIdx.x) * 8;
    float4a u0 = *(const float4a*)(s + i);
    float4a u1 = *(const float4a*)(s + i + 4);
    uint4a w = (uint4a){pk_bf16(u0[0], u0[1]), pk_bf16(u0[2], u0[3]),
                        pk_bf16(u1[0], u1[1]), pk_bf16(u1[2], u1[3])};
    *(uint4a*)(d + i) = w;
}

// ---- GEMM core: Y[m,n] = sum_k X[m,k] * Wt[n,k] + bias[n] ----
// (round-4 version, PASSED at 458 us total: proj3 dropped out of top-5)
// 128x128 tile, BK=32, 4-slot LDS ring (64 KB) with COUNTED vmcnt:
// prefetch 3 K-steps ahead; steady state waits only vmcnt(12).
template<bool OUTF32>
__device__ __forceinline__ void gemm_body(
    const ushort_t* X, const ushort_t* Wt, const float* bias,
    void* Yv, int mode, int tileM, int tileN)
{
    __shared__ __align__(16) ushort_t As[4][4096];   // 8 KB per slot
    __shared__ __align__(16) ushort_t Bs[4][4096];   // 8 KB per slot
    const int tid = threadIdx.x;
    const int lane = tid & 63;
    const int quad = lane >> 4;
    const int l15 = lane & 15;
    const int wid = tid >> 6;
    const int wm = (wid >> 1) * 64;
    const int wn = (wid & 1) * 64;

    float4a acc[4][4];
    #pragma unroll
    for (int i = 0; i < 4; i++)
        #pragma unroll
        for (int j = 0; j < 4; j++)
            acc[i][j] = (float4a){0.f, 0.f, 0.f, 0.f};

    const ushort_t* pA0 = X  + (size_t)(tileM + (tid & 127)) * E_SZ + (tid >> 7) * 8;
    const ushort_t* pA1 = X  + (size_t)(tileM + (tid & 127)) * E_SZ + ((tid >> 7) + 2) * 8;
    const ushort_t* pB0 = Wt + (size_t)(tileN + (tid & 127)) * E_SZ + (tid >> 7) * 8;
    const ushort_t* pB1 = Wt + (size_t)(tileN + (tid & 127)) * E_SZ + ((tid >> 7) + 2) * 8;
    const int d0 = tid * 8;
    const int d1 = (256 + tid) * 8;

#define STAGE(SLOT) do { \
    async_copy16(pA0, &As[SLOT][d0]); \
    async_copy16(pA1, &As[SLOT][d1]); \
    async_copy16(pB0, &Bs[SLOT][d0]); \
    async_copy16(pB1, &Bs[SLOT][d1]); \
    pA0 += 32; pA1 += 32; pB0 += 32; pB1 += 32; } while (0)

    STAGE(0); STAGE(1); STAGE(2);

#define KTILE(SLOT, DOSTAGE, VMS) do { \
    asm volatile("s_waitcnt lgkmcnt(0)" ::: "memory"); \
    __builtin_amdgcn_s_barrier(); \
    asm volatile("" ::: "memory"); \
    if (DOSTAGE) STAGE(((SLOT) + 3) & 3); \
    asm volatile("s_waitcnt vmcnt(" #VMS ")" ::: "memory"); \
    __builtin_amdgcn_s_barrier(); \
    asm volatile("" ::: "memory"); \
    { \
        short8 a[4], b[4]; \
        _Pragma("unroll") \
        for (int mt = 0; mt < 4; mt++) \
            a[mt] = *(const short8*)&As[SLOT][quad * 1024 + (wm + mt * 16 + l15) * 8]; \
        _Pragma("unroll") \
        for (int nt = 0; nt < 4; nt++) \
            b[nt] = *(const short8*)&Bs[SLOT][quad * 1024 + (wn + nt * 16 + l15) * 8]; \
        __builtin_amdgcn_s_setprio(1); \
        _Pragma("unroll") \
        for (int mt = 0; mt < 4; mt++) \
            _Pragma("unroll") \
            for (int nt = 0; nt < 4; nt++) \
                acc[mt][nt] = __builtin_amdgcn_mfma_f32_16x16x32_bf16( \
                    a[mt], b[nt], acc[mt][nt], 0, 0, 0); \
        __builtin_amdgcn_s_setprio(0); \
    } } while (0)

    #pragma unroll 1
    for (int j = 0; j < 28; j += 4) {
        KTILE(0, true, 12);
        KTILE(1, true, 12);
        KTILE(2, true, 12);
        KTILE(3, true, 12);
    }
    KTILE(0, true, 12);
    KTILE(1, false, 8);
    KTILE(2, false, 4);
    KTILE(3, false, 0);
#undef KTILE
#undef STAGE

    #pragma unroll
    for (int nt = 0; nt < 4; nt++) {
        int n = tileN + wn + nt * 16 + l15;
        float bv = bias[n];
        #pragma unroll
        for (int mt = 0; mt < 4; mt++) {
            #pragma unroll
            for (int r = 0; r < 4; r++) {
                int m = tileM + wm + mt * 16 + quad * 4 + r;
                float v = acc[mt][nt][r] + bv;
                if constexpr (OUTF32) {
                    ((float*)Yv)[(size_t)m * E_SZ + n] = v;
                } else {
                    ushort_t* Y = (ushort_t*)Yv;
                    if (mode == 0) {
                        Y[(size_t)m * E_SZ + n] = f2bf(v);
                    } else {
                        int bb = m >> 11, s = m & 2047;
                        Y[((size_t)(bb * E_SZ + n)) * S_SZ + s] = f2bf(v);
                    }
                }
            }
        }
    }
}

// fused Q/K/V projections: z selects input/weight/bias/output.
__global__ __launch_bounds__(256, 2) void proj3(
    const ushort_t* __restrict__ x0, const ushort_t* __restrict__ x1,
    const ushort_t* __restrict__ x2, const ushort_t* __restrict__ Wt,
    const float* __restrict__ b0, const float* __restrict__ b1,
    const float* __restrict__ b2, ushort_t* __restrict__ y0,
    ushort_t* __restrict__ y1, ushort_t* __restrict__ y2)
{
    const ushort_t* X; const float* bias; ushort_t* Y; int mode = 0;
    switch (blockIdx.z) {
        case 0: X = x0; bias = b0; Y = y0; break;
        case 1: X = x1; bias = b1; Y = y1; break;
        default: X = x2; bias = b2; Y = y2; mode = 1; break;
    }
    gemm_body<false>(X, Wt + (size_t)blockIdx.z * E_SZ * E_SZ, bias, Y, mode,
                     blockIdx.y * 128, blockIdx.x * 128);
}

// final output projection: bf16 X -> fp32 Y
__global__ __launch_bounds__(256, 2) void gemm_out(
    const ushort_t* __restrict__ X, const ushort_t* __restrict__ Wt,
    const float* __restrict__ bias, float* __restrict__ Y)
{
    gemm_body<true>(X, Wt, bias, Y, 0, blockIdx.y * 128, blockIdx.x * 128);
}

// ---- kernel 3: flash attention (round-11) ----
// Base = round-4 structure (140 us, known-good): 64 KB LDS, P^T round-trip
// through [128][128] swizzled PQ amortized ONCE per kt (round-5's per-kk
// slice regressed: +8e6 bank conflicts + 4x serial LDS chains).
// Surgical VALU cuts only (round-4 PMC: VALUBusy 51% = largest pipe):
//  * st init via zero-C MFMA at ks=0 (kills 64 v_mov per kt)
//  * incremental K/V staging base pointers (p-offsets are compile-time;
//    per-kt address math -> two pointer increments)
//  * defer-max (validated r5), max3 rmax chains (validated r5),
//    setprio around MFMA clusters (validated r5)
__global__ __launch_bounds__(256) void attn(
    const ushort_t* __restrict__ Q, const ushort_t* __restrict__ K,
    const ushort_t* __restrict__ V, ushort_t* __restrict__ ctx)
{
    // PQ: Qs [8][128][8] (8192) at kt==0, then Ps swizzled [128][128]
    __shared__ __align__(16) ushort_t smem[32768];   // 64 KB
    ushort_t* PQ = smem;
    ushort_t* Ks = smem + 16384;         // [g(8)][row(128)][8]
    ushort_t* Vt = smem + 24576;         // swizzled [d(64)][c(128)]

    const int tid = threadIdx.x;
    const int lane = tid & 63;
    const int quad = lane >> 4;
    const int l15 = lane & 15;
    const int wid = tid >> 6;
    const int qt = blockIdx.x;              // 0..15
    const int bh = blockIdx.y;              // 0..63
    const int b = bh >> 4, h = bh & 15;
    const int s0 = qt * 128;
    const int wq = wid * 32;
    const float CE = 0.18033688011f;        // 0.125 * log2(e)

    // stage Q once (completion covered by first in-loop barrier)
    for (int p = 0; p < 4; p++) {
        int L = p * 256 + tid;
        int g = L >> 7, r = L & 127;
        const ushort_t* src = Q + ((size_t)(b * S_SZ + s0 + r)) * E_SZ + h * HD_SZ + g * 8;
        async_copy16(src, &PQ[L * 8]);
    }

    // incremental staging pointers (kt-invariant decomposition):
    // K: L = p*256+tid -> row = tid&127 (same all p), g = p*2 + (tid>>7)
    //    => src = kBase + p*16; LDS dst = tid*16B + p*4096B
    // V: c = p*256+tid -> d = p*16 + (tid>>4), cc = tid&15
    //    => src = vBase + p*16*S; dst = vDst + p*2048 elems
    const ushort_t* kBase = K + ((size_t)(b * S_SZ + (tid & 127))) * E_SZ
                              + h * HD_SZ + (tid >> 7) * 8;
    const ushort_t* vBase = V + ((size_t)(b * E_SZ + h * HD_SZ + (tid >> 4))) * S_SZ
                              + (tid & 15) * 8;
    const int kDst = tid * 8;
    const int vDst = (tid >> 4) * 128 + (((tid & 15) ^ ((tid >> 4) & 7)) << 3);

    float4a st[8][2];       // S^T acc: mt over kidx(8 x16), nt over q(2 x16)
    float4a o[4][2];        // O^T acc: mt over d(4 x16), nt over q(2 x16)
    for (int mt = 0; mt < 4; mt++)
        for (int nt = 0; nt < 2; nt++)
            o[mt][nt] = (float4a){0.f, 0.f, 0.f, 0.f};
    float mrow[2] = {-1e30f, -1e30f};   // raw-score units
    float lrow[2] = {0.f, 0.f};
    short8 qf[2][2];

    for (int kt = 0; kt < 16; kt++) {
        // stage K tile (async, lane-consecutive 16B)
        #pragma unroll
        for (int p = 0; p < 4; p++)
            async_copy16(kBase + p * 16, &Ks[kDst + p * 2048]);
        // stage V^T tile (swizzled rows of 128)
        #pragma unroll
        for (int p = 0; p < 4; p++) {
            short8 val = *(const short8*)(vBase + (size_t)p * (16 * S_SZ));
            *(short8*)&Vt[vDst + p * 2048] = val;
        }
        kBase += 128 * E_SZ;
        vBase += 128;
        __syncthreads();
        if (kt == 0) {
            for (int ks = 0; ks < 2; ks++)
                for (int nt = 0; nt < 2; nt++)
                    qf[ks][nt] = *(const short8*)&PQ[(ks * 4 + quad) * 1024 + (wq + nt * 16 + l15) * 8];
            __syncthreads();   // Ps writes below alias Qs; wait for all qf loads
        }

        // S^T[kidx][q] = sum_d K[kidx][d] * Q[q][d]; ks=0 uses zero-C init
        __builtin_amdgcn_s_setprio(1);
        {
            const float4a z4 = (float4a){0.f, 0.f, 0.f, 0.f};
            #pragma unroll
            for (int mt = 0; mt < 8; mt++) {
                short8 kf = *(const short8*)&Ks[quad * 1024 + (mt * 16 + l15) * 8];
                #pragma unroll
                for (int nt = 0; nt < 2; nt++)
                    st[mt][nt] = __builtin_amdgcn_mfma_f32_16x16x32_bf16(
                        kf, qf[0][nt], z4, 0, 0, 0);
            }
            #pragma unroll
            for (int mt = 0; mt < 8; mt++) {
                short8 kf = *(const short8*)&Ks[(4 + quad) * 1024 + (mt * 16 + l15) * 8];
                #pragma unroll
                for (int nt = 0; nt < 2; nt++)
                    st[mt][nt] = __builtin_amdgcn_mfma_f32_16x16x32_bf16(
                        kf, qf[1][nt], st[mt][nt], 0, 0, 0);
            }
        }
        __builtin_amdgcn_s_setprio(0);

        // row max via max3-fusable chains, cross-quad reduce
        float rmax[2] = {-1e30f, -1e30f};
        for (int mt = 0; mt < 8; mt++)
            for (int nt = 0; nt < 2; nt++) {
                rmax[nt] = fmaxf(fmaxf(rmax[nt], st[mt][nt][0]), st[mt][nt][1]);
                rmax[nt] = fmaxf(fmaxf(rmax[nt], st[mt][nt][2]), st[mt][nt][3]);
            }
        for (int nt = 0; nt < 2; nt++) {
            rmax[nt] = fmaxf(rmax[nt], __shfl_xor(rmax[nt], 16));
            rmax[nt] = fmaxf(rmax[nt], __shfl_xor(rmax[nt], 32));
        }
        // defer-max (T13, validated r5): rescale only when max grew > 44
        // raw (= 8 in exp2 domain; P bounded by 2^8, bf16-safe)
        float alpha[2] = {1.f, 1.f};
        int grew = !__all((rmax[0] - mrow[0] <= 44.0f) &&
                          (rmax[1] - mrow[1] <= 44.0f));
        if (grew) {
            float nm0 = fmaxf(mrow[0], rmax[0]);
            float nm1 = fmaxf(mrow[1], rmax[1]);
            alpha[0] = EXP2F((mrow[0] - nm0) * CE);
            alpha[1] = EXP2F((mrow[1] - nm1) * CE);
            mrow[0] = nm0; mrow[1] = nm1;
            for (int mt = 0; mt < 4; mt++)
                for (int nt = 0; nt < 2; nt++)
                    for (int r = 0; r < 4; r++)
                        o[mt][nt][r] *= alpha[nt];
        }
        float mc[2] = {mrow[0] * CE, mrow[1] * CE};
        float rsum[2] = {0.f, 0.f};

        // exp, row-sum, perm-pack to bf16, swizzled LDS write (b64).
        // Each wave touches only its own q rows -> no barrier needed.
        for (int mt = 0; mt < 8; mt++)
            for (int nt = 0; nt < 2; nt++) {
                float e0 = EXP2F(fmaf(st[mt][nt][0], CE, -mc[nt]));
                float e1 = EXP2F(fmaf(st[mt][nt][1], CE, -mc[nt]));
                float e2 = EXP2F(fmaf(st[mt][nt][2], CE, -mc[nt]));
                float e3 = EXP2F(fmaf(st[mt][nt][3], CE, -mc[nt]));
                rsum[nt] += (e0 + e1) + (e2 + e3);
                uint2a pp = (uint2a){pk_bf16(e0, e1), pk_bf16(e2, e3)};
                int row = wq + nt * 16 + l15;
                // element col = mt*16 + quad*4 -> grp = 2mt + (quad>>1)
                *(uint2a*)&PQ[row * 128 + (((2 * mt + (quad >> 1)) ^ (row & 7)) << 3) + (quad & 1) * 4] = pp;
            }
        for (int nt = 0; nt < 2; nt++) {
            rsum[nt] += __shfl_xor(rsum[nt], 16);
            rsum[nt] += __shfl_xor(rsum[nt], 32);
            lrow[nt] = lrow[nt] * alpha[nt] + rsum[nt];
        }

        // O^T[d][q] += sum_kidx V^T[d][kidx] * P^T[kidx][q]  (16x16x32)
        for (int kk = 0; kk < 4; kk++) {
            int swz = ((kk * 4 + quad) ^ (l15 & 7)) << 3;   // row&7 == l15&7 for all rows used
            short8 a[4], pb[2];
            for (int mt = 0; mt < 4; mt++)
                a[mt] = *(const short8*)&Vt[(mt * 16 + l15) * 128 + swz];
            for (int nt = 0; nt < 2; nt++)
                pb[nt] = *(const short8*)&PQ[(wq + nt * 16 + l15) * 128 + swz];
            __builtin_amdgcn_s_setprio(1);
            for (int mt = 0; mt < 4; mt++)
                for (int nt = 0; nt < 2; nt++)
                    o[mt][nt] = __builtin_amdgcn_mfma_f32_16x16x32_bf16(
                        a[mt], pb[nt], o[mt][nt], 0, 0, 0);
            __builtin_amdgcn_s_setprio(0);
        }
        __syncthreads();
    }

    // epilogue: ctx[b, s, h*64+d] = O^T[d][q] / l[q]   (8B packed stores)
    for (int nt = 0; nt < 2; nt++) {
        float inv = 1.f / lrow[nt];
        int s = s0 + wq + nt * 16 + l15;
        size_t base = ((size_t)(b * S_SZ + s)) * E_SZ + h * HD_SZ;
        for (int mt = 0; mt < 4; mt++) {
            int d = mt * 16 + quad * 4;
            uint2a w = (uint2a){pk_bf16(o[mt][nt][0] * inv, o[mt][nt][1] * inv),
                                pk_bf16(o[mt][nt][2] * inv, o[mt][nt][3] * inv)};
            *(uint2a*)&ctx[base + d] = w;
        }
    }
}

extern "C" void kernel_launch(void* const* d_in, const int* in_sizes, int n_in,
                              void* d_out, int out_size, void* d_ws, size_t ws_size,
                              hipStream_t stream) {
    const float* q_in = (const float*)d_in[0];
    const float* k_in = (const float*)d_in[1];
    const float* v_in = (const float*)d_in[2];
    const float* Wq = (const float*)d_in[3];
    const float* bq = (const float*)d_in[4];
    const float* Wk = (const float*)d_in[5];
    const float* bk = (const float*)d_in[6];
    const float* Wv = (const float*)d_in[7];
    const float* bv = (const float*)d_in[8];
    const float* Wo = (const float*)d_in[9];
    const float* bo = (const float*)d_in[10];

    ushort_t* ws = (ushort_t*)d_ws;
    const size_t WMAT = (size_t)E_SZ * E_SZ;           // 1M elements
    const size_t TEN = (size_t)B_SZ * S_SZ * E_SZ;     // 8M elements
    ushort_t* Wt = ws;                 // 4 transposed bf16 weights (8 MB)
    ushort_t* qb = ws + 4 * WMAT;      // bf16 copies of inputs
    ushort_t* kb = qb + TEN;
    ushort_t* vb = kb + TEN;
    ushort_t* qp = vb + TEN;           // projected Q/K/V
    ushort_t* kp = qp + TEN;
    ushort_t* vp = kp + TEN;           // stored [B, E, S]
    ushort_t* cx = qb;                 // ctx aliases qb (dead after proj3)

    transpose4<<<dim3(32, 32, 4), dim3(32, 8), 0, stream>>>(Wq, Wk, Wv, Wo, Wt);
    cvt3<<<dim3(4096, 3), 256, 0, stream>>>(q_in, k_in, v_in, qb, kb, vb);
    proj3<<<dim3(8, 64, 3), 256, 0, stream>>>(qb, kb, vb, Wt, bq, bk, bv, qp, kp, vp);
    attn<<<dim3(16, 64), 256, 0, stream>>>(qp, kp, vp, cx);
    gemm_out<<<dim3(8, 64), 256, 0, stream>>>(cx, Wt + 3 * WMAT, bo, (float*)d_out);
}

// Round 7
// 460.974 us; speedup vs baseline: 1.0171x; 1.0012x over previous
//
#include <hip/hip_runtime.h>
#include <math.h>

typedef unsigned short ushort_t;
typedef unsigned int uint_t;
typedef short short8 __attribute__((ext_vector_type(8)));
typedef float float4a __attribute__((ext_vector_type(4)));
typedef uint_t uint4a __attribute__((ext_vector_type(4)));
typedef uint_t uint2a __attribute__((ext_vector_type(2)));

#define B_SZ 4
#define S_SZ 2048
#define E_SZ 1024
#define H_SZ 16
#define HD_SZ 64

#if __has_builtin(__builtin_amdgcn_exp2f)
#define EXP2F(x) __builtin_amdgcn_exp2f(x)
#else
#define EXP2F(x) exp2f(x)
#endif

// ---- helpers ----
__device__ __forceinline__ ushort_t f2bf(float f) {
    uint_t u = __builtin_bit_cast(uint_t, f);
    u = (u + 0x7fff + ((u >> 16) & 1)) >> 16;
    return (ushort_t)u;
}
// pack 2 fp32 -> 2 bf16 (round half-up) in one v_perm_b32
__device__ __forceinline__ uint_t pk_bf16(float a, float b) {
    uint_t ua = __builtin_bit_cast(uint_t, a) + 0x8000u;
    uint_t ub = __builtin_bit_cast(uint_t, b) + 0x8000u;
#if __has_builtin(__builtin_amdgcn_perm)
    return __builtin_amdgcn_perm(ub, ua, 0x07060302u);
#else
    return (ua >> 16) | (ub & 0xffff0000u);
#endif
}
__device__ __forceinline__ void async_copy16(const void* g, void* l) {
    __builtin_amdgcn_global_load_lds(
        (const __attribute__((address_space(1))) void*)g,
        (__attribute__((address_space(3))) void*)l, 16, 0, 0);
}

// ---- kernel 1: transpose 4 fp32 weight matrices (E x E) -> bf16 ----
__global__ __launch_bounds__(256) void transpose4(
    const float* __restrict__ W0, const float* __restrict__ W1,
    const float* __restrict__ W2, const float* __restrict__ W3,
    ushort_t* __restrict__ out)
{
    const float* src;
    switch (blockIdx.z) {
        case 0: src = W0; break;
        case 1: src = W1; break;
        case 2: src = W2; break;
        default: src = W3; break;
    }
    ushort_t* dst = out + (size_t)blockIdx.z * (E_SZ * E_SZ);
    __shared__ ushort_t t[32][33];
    int x = blockIdx.x * 32 + threadIdx.x;
    int y0 = blockIdx.y * 32;
    for (int i = threadIdx.y; i < 32; i += 8)
        t[i][threadIdx.x] = f2bf(src[(size_t)(y0 + i) * E_SZ + x]);
    __syncthreads();
    int yy = blockIdx.x * 32;
    int xx = y0 + threadIdx.x;
    for (int i = threadIdx.y; i < 32; i += 8)
        dst[(size_t)(yy + i) * E_SZ + xx] = t[threadIdx.x][i];
}

// ---- kernel 1b: bulk fp32 -> bf16 convert of query/key/value ----
__global__ __launch_bounds__(256) void cvt3(
    const float* __restrict__ s0, const float* __restrict__ s1,
    const float* __restrict__ s2, ushort_t* __restrict__ d0,
    ushort_t* __restrict__ d1, ushort_t* __restrict__ d2)
{
    const float* s; ushort_t* d;
    switch (blockIdx.y) {
        case 0: s = s0; d = d0; break;
        case 1: s = s1; d = d1; break;
        default: s = s2; d = d2; break;
    }
    size_t i = ((size_t)blockIdx.x * 256 + threadIdx.x) * 8;
    float4a u0 = *(const float4a*)(s + i);
    float4a u1 = *(const float4a*)(s + i + 4);
    uint4a w = (uint4a){pk_bf16(u0[0], u0[1]), pk_bf16(u0[2], u0[3]),
                        pk_bf16(u1[0], u1[1]), pk_bf16(u1[2], u1[3])};
    *(uint4a*)(d + i) = w;
}

// ---- GEMM core: Y[m,n] = sum_k X[m,k] * Wt[n,k] + bias[n] ----
// (round-4 version, kept byte-identical)
// 128x128 tile, BK=32, 4-slot LDS ring (64 KB) with COUNTED vmcnt:
// prefetch 3 K-steps ahead; steady state waits only vmcnt(12).
template<bool OUTF32>
__device__ __forceinline__ void gemm_body(
    const ushort_t* X, const ushort_t* Wt, const float* bias,
    void* Yv, int mode, int tileM, int tileN)
{
    __shared__ __align__(16) ushort_t As[4][4096];   // 8 KB per slot
    __shared__ __align__(16) ushort_t Bs[4][4096];   // 8 KB per slot
    const int tid = threadIdx.x;
    const int lane = tid & 63;
    const int quad = lane >> 4;
    const int l15 = lane & 15;
    const int wid = tid >> 6;
    const int wm = (wid >> 1) * 64;
    const int wn = (wid & 1) * 64;

    float4a acc[4][4];
    #pragma unroll
    for (int i = 0; i < 4; i++)
        #pragma unroll
        for (int j = 0; j < 4; j++)
            acc[i][j] = (float4a){0.f, 0.f, 0.f, 0.f};

    const ushort_t* pA0 = X  + (size_t)(tileM + (tid & 127)) * E_SZ + (tid >> 7) * 8;
    const ushort_t* pA1 = X  + (size_t)(tileM + (tid & 127)) * E_SZ + ((tid >> 7) + 2) * 8;
    const ushort_t* pB0 = Wt + (size_t)(tileN + (tid & 127)) * E_SZ + (tid >> 7) * 8;
    const ushort_t* pB1 = Wt + (size_t)(tileN + (tid & 127)) * E_SZ + ((tid >> 7) + 2) * 8;
    const int d0 = tid * 8;
    const int d1 = (256 + tid) * 8;

#define STAGE(SLOT) do { \
    async_copy16(pA0, &As[SLOT][d0]); \
    async_copy16(pA1, &As[SLOT][d1]); \
    async_copy16(pB0, &Bs[SLOT][d0]); \
    async_copy16(pB1, &Bs[SLOT][d1]); \
    pA0 += 32; pA1 += 32; pB0 += 32; pB1 += 32; } while (0)

    STAGE(0); STAGE(1); STAGE(2);

#define KTILE(SLOT, DOSTAGE, VMS) do { \
    asm volatile("s_waitcnt lgkmcnt(0)" ::: "memory"); \
    __builtin_amdgcn_s_barrier(); \
    asm volatile("" ::: "memory"); \
    if (DOSTAGE) STAGE(((SLOT) + 3) & 3); \
    asm volatile("s_waitcnt vmcnt(" #VMS ")" ::: "memory"); \
    __builtin_amdgcn_s_barrier(); \
    asm volatile("" ::: "memory"); \
    { \
        short8 a[4], b[4]; \
        _Pragma("unroll") \
        for (int mt = 0; mt < 4; mt++) \
            a[mt] = *(const short8*)&As[SLOT][quad * 1024 + (wm + mt * 16 + l15) * 8]; \
        _Pragma("unroll") \
        for (int nt = 0; nt < 4; nt++) \
            b[nt] = *(const short8*)&Bs[SLOT][quad * 1024 + (wn + nt * 16 + l15) * 8]; \
        __builtin_amdgcn_s_setprio(1); \
        _Pragma("unroll") \
        for (int mt = 0; mt < 4; mt++) \
            _Pragma("unroll") \
            for (int nt = 0; nt < 4; nt++) \
                acc[mt][nt] = __builtin_amdgcn_mfma_f32_16x16x32_bf16( \
                    a[mt], b[nt], acc[mt][nt], 0, 0, 0); \
        __builtin_amdgcn_s_setprio(0); \
    } } while (0)

    #pragma unroll 1
    for (int j = 0; j < 28; j += 4) {
        KTILE(0, true, 12);
        KTILE(1, true, 12);
        KTILE(2, true, 12);
        KTILE(3, true, 12);
    }
    KTILE(0, true, 12);
    KTILE(1, false, 8);
    KTILE(2, false, 4);
    KTILE(3, false, 0);
#undef KTILE
#undef STAGE

    #pragma unroll
    for (int nt = 0; nt < 4; nt++) {
        int n = tileN + wn + nt * 16 + l15;
        float bv = bias[n];
        #pragma unroll
        for (int mt = 0; mt < 4; mt++) {
            #pragma unroll
            for (int r = 0; r < 4; r++) {
                int m = tileM + wm + mt * 16 + quad * 4 + r;
                float v = acc[mt][nt][r] + bv;
                if constexpr (OUTF32) {
                    ((float*)Yv)[(size_t)m * E_SZ + n] = v;
                } else {
                    ushort_t* Y = (ushort_t*)Yv;
                    if (mode == 0) {
                        Y[(size_t)m * E_SZ + n] = f2bf(v);
                    } else {
                        int bb = m >> 11, s = m & 2047;
                        Y[((size_t)(bb * E_SZ + n)) * S_SZ + s] = f2bf(v);
                    }
                }
            }
        }
    }
}

// fused Q/K/V projections: z selects input/weight/bias/output.
__global__ __launch_bounds__(256, 2) void proj3(
    const ushort_t* __restrict__ x0, const ushort_t* __restrict__ x1,
    const ushort_t* __restrict__ x2, const ushort_t* __restrict__ Wt,
    const float* __restrict__ b0, const float* __restrict__ b1,
    const float* __restrict__ b2, ushort_t* __restrict__ y0,
    ushort_t* __restrict__ y1, ushort_t* __restrict__ y2)
{
    const ushort_t* X; const float* bias; ushort_t* Y; int mode = 0;
    switch (blockIdx.z) {
        case 0: X = x0; bias = b0; Y = y0; break;
        case 1: X = x1; bias = b1; Y = y1; break;
        default: X = x2; bias = b2; Y = y2; mode = 1; break;
    }
    gemm_body<false>(X, Wt + (size_t)blockIdx.z * E_SZ * E_SZ, bias, Y, mode,
                     blockIdx.y * 128, blockIdx.x * 128);
}

// final output projection: bf16 X -> fp32 Y
__global__ __launch_bounds__(256, 2) void gemm_out(
    const ushort_t* __restrict__ X, const ushort_t* __restrict__ Wt,
    const float* __restrict__ bias, float* __restrict__ Y)
{
    gemm_body<true>(X, Wt, bias, Y, 0, blockIdx.y * 128, blockIdx.x * 128);
}

// ---- kernel 3: flash attention (round-12: 48 KB LDS, P in 2 halves) ----
// Round-6 PMC: dur 141us, VALUBusy 48%, MfmaUtil 21%, Occupancy 21%
// (2 blocks/CU at 64 KB LDS => only 2 waves/SIMD; overlap-bound).
// Change: P buffer [128][128] (32 KB) -> [128][64] (16 KB), processed as
// two 64-kidx halves per kt.  Same swizzle family as the validated
// 128-wide version: write ch = mt_l*2+(quad>>1) in 0..7, read ch =
// kk_l*4+quad in 0..7, both XOR (row&7) -> bijective per row, bank-even
// on b64 write and b128 read.  Only 2 write->read chains per kt (round-5's
// failure was 4 chains x 4-way-conflicted 32-wide slices).
// LDS 64->48 KB => 3 blocks/CU (12 waves/CU, +50% TLP).
// Q (128x64 = exactly 16 KB) still prologue-staged into the P buffer.
// Everything else = round-6 (incremental pointers, defer-max, zero-C
// init, max3 chains, setprio).  VGPR must stay <= 128 (4 waves/SIMD cap).
__global__ __launch_bounds__(256) void attn(
    const ushort_t* __restrict__ Q, const ushort_t* __restrict__ K,
    const ushort_t* __restrict__ V, ushort_t* __restrict__ ctx)
{
    __shared__ __align__(16) ushort_t smem[24576];   // 48 KB
    ushort_t* PQ = smem;                 // Qs [8][128][8] then P halves [128][64]
    ushort_t* Ks = smem + 8192;          // [g(8)][row(128)][8]  16 KB
    ushort_t* Vt = smem + 16384;         // swizzled [d(64)][c(128)] 16 KB

    const int tid = threadIdx.x;
    const int lane = tid & 63;
    const int quad = lane >> 4;
    const int l15 = lane & 15;
    const int wid = tid >> 6;
    const int qt = blockIdx.x;              // 0..15
    const int bh = blockIdx.y;              // 0..63
    const int b = bh >> 4, h = bh & 15;
    const int s0 = qt * 128;
    const int wq = wid * 32;
    const float CE = 0.18033688011f;        // 0.125 * log2(e)

    // stage Q once (completion covered by first in-loop barrier)
    for (int p = 0; p < 4; p++) {
        int L = p * 256 + tid;
        int g = L >> 7, r = L & 127;
        const ushort_t* src = Q + ((size_t)(b * S_SZ + s0 + r)) * E_SZ + h * HD_SZ + g * 8;
        async_copy16(src, &PQ[L * 8]);
    }

    // incremental staging pointers (kt-invariant decomposition)
    const ushort_t* kBase = K + ((size_t)(b * S_SZ + (tid & 127))) * E_SZ
                              + h * HD_SZ + (tid >> 7) * 8;
    const ushort_t* vBase = V + ((size_t)(b * E_SZ + h * HD_SZ + (tid >> 4))) * S_SZ
                              + (tid & 15) * 8;
    const int kDst = tid * 8;
    const int vDst = (tid >> 4) * 128 + (((tid & 15) ^ ((tid >> 4) & 7)) << 3);

    float4a st[8][2];       // S^T acc: mt over kidx(8 x16), nt over q(2 x16)
    float4a o[4][2];        // O^T acc: mt over d(4 x16), nt over q(2 x16)
    for (int mt = 0; mt < 4; mt++)
        for (int nt = 0; nt < 2; nt++)
            o[mt][nt] = (float4a){0.f, 0.f, 0.f, 0.f};
    float mrow[2] = {-1e30f, -1e30f};   // raw-score units
    float lrow[2] = {0.f, 0.f};
    short8 qf[2][2];

    for (int kt = 0; kt < 16; kt++) {
        // stage K tile (async, lane-consecutive 16B)
        #pragma unroll
        for (int p = 0; p < 4; p++)
            async_copy16(kBase + p * 16, &Ks[kDst + p * 2048]);
        // stage V^T tile (swizzled rows of 128)
        #pragma unroll
        for (int p = 0; p < 4; p++) {
            short8 val = *(const short8*)(vBase + (size_t)p * (16 * S_SZ));
            *(short8*)&Vt[vDst + p * 2048] = val;
        }
        kBase += 128 * E_SZ;
        vBase += 128;
        __syncthreads();
        if (kt == 0) {
            for (int ks = 0; ks < 2; ks++)
                for (int nt = 0; nt < 2; nt++)
                    qf[ks][nt] = *(const short8*)&PQ[(ks * 4 + quad) * 1024 + (wq + nt * 16 + l15) * 8];
            __syncthreads();   // P-half writes below alias Qs; wait for all qf loads
        }

        // S^T[kidx][q] = sum_d K[kidx][d] * Q[q][d]; ks=0 uses zero-C init
        __builtin_amdgcn_s_setprio(1);
        {
            const float4a z4 = (float4a){0.f, 0.f, 0.f, 0.f};
            #pragma unroll
            for (int mt = 0; mt < 8; mt++) {
                short8 kf = *(const short8*)&Ks[quad * 1024 + (mt * 16 + l15) * 8];
                #pragma unroll
                for (int nt = 0; nt < 2; nt++)
                    st[mt][nt] = __builtin_amdgcn_mfma_f32_16x16x32_bf16(
                        kf, qf[0][nt], z4, 0, 0, 0);
            }
            #pragma unroll
            for (int mt = 0; mt < 8; mt++) {
                short8 kf = *(const short8*)&Ks[(4 + quad) * 1024 + (mt * 16 + l15) * 8];
                #pragma unroll
                for (int nt = 0; nt < 2; nt++)
                    st[mt][nt] = __builtin_amdgcn_mfma_f32_16x16x32_bf16(
                        kf, qf[1][nt], st[mt][nt], 0, 0, 0);
            }
        }
        __builtin_amdgcn_s_setprio(0);

        // row max via max3-fusable chains, cross-quad reduce
        float rmax[2] = {-1e30f, -1e30f};
        for (int mt = 0; mt < 8; mt++)
            for (int nt = 0; nt < 2; nt++) {
                rmax[nt] = fmaxf(fmaxf(rmax[nt], st[mt][nt][0]), st[mt][nt][1]);
                rmax[nt] = fmaxf(fmaxf(rmax[nt], st[mt][nt][2]), st[mt][nt][3]);
            }
        for (int nt = 0; nt < 2; nt++) {
            rmax[nt] = fmaxf(rmax[nt], __shfl_xor(rmax[nt], 16));
            rmax[nt] = fmaxf(rmax[nt], __shfl_xor(rmax[nt], 32));
        }
        // defer-max (T13): rescale only when max grew > 44 raw
        float alpha[2] = {1.f, 1.f};
        int grew = !__all((rmax[0] - mrow[0] <= 44.0f) &&
                          (rmax[1] - mrow[1] <= 44.0f));
        if (grew) {
            float nm0 = fmaxf(mrow[0], rmax[0]);
            float nm1 = fmaxf(mrow[1], rmax[1]);
            alpha[0] = EXP2F((mrow[0] - nm0) * CE);
            alpha[1] = EXP2F((mrow[1] - nm1) * CE);
            mrow[0] = nm0; mrow[1] = nm1;
            for (int mt = 0; mt < 4; mt++)
                for (int nt = 0; nt < 2; nt++)
                    for (int r = 0; r < 4; r++)
                        o[mt][nt][r] *= alpha[nt];
        }
        float mc[2] = {mrow[0] * CE, mrow[1] * CE};
        float rsum[2] = {0.f, 0.f};

        // two 64-kidx halves: exp+pack+write [128][64], then 2 PV kk-groups.
        // Rows are wave-private; same-wave LDS write->read is in-order.
        #pragma unroll
        for (int hf = 0; hf < 2; hf++) {
            #pragma unroll
            for (int mtL = 0; mtL < 4; mtL++) {
                int mt = hf * 4 + mtL;
                #pragma unroll
                for (int nt = 0; nt < 2; nt++) {
                    float e0 = EXP2F(fmaf(st[mt][nt][0], CE, -mc[nt]));
                    float e1 = EXP2F(fmaf(st[mt][nt][1], CE, -mc[nt]));
                    float e2 = EXP2F(fmaf(st[mt][nt][2], CE, -mc[nt]));
                    float e3 = EXP2F(fmaf(st[mt][nt][3], CE, -mc[nt]));
                    rsum[nt] += (e0 + e1) + (e2 + e3);
                    uint2a pp = (uint2a){pk_bf16(e0, e1), pk_bf16(e2, e3)};
                    int row = wq + nt * 16 + l15;
                    // col = mt*16+quad*4+r  ->  ch = mtL*2+(quad>>1), +4B if quad odd
                    *(uint2a*)&PQ[row * 64 + (((mtL * 2 + (quad >> 1)) ^ (row & 7)) << 3) + (quad & 1) * 4] = pp;
                }
            }
            #pragma unroll
            for (int kkL = 0; kkL < 2; kkL++) {
                int kk = hf * 2 + kkL;
                int swzV = ((kk * 4 + quad) ^ (l15 & 7)) << 3;
                short8 a[4], pb[2];
                #pragma unroll
                for (int mt = 0; mt < 4; mt++)
                    a[mt] = *(const short8*)&Vt[(mt * 16 + l15) * 128 + swzV];
                #pragma unroll
                for (int nt = 0; nt < 2; nt++) {
                    int row = wq + nt * 16 + l15;
                    pb[nt] = *(const short8*)&PQ[row * 64 + (((kkL * 4 + quad) ^ (row & 7)) << 3)];
                }
                __builtin_amdgcn_s_setprio(1);
                #pragma unroll
                for (int mt = 0; mt < 4; mt++)
                    #pragma unroll
                    for (int nt = 0; nt < 2; nt++)
                        o[mt][nt] = __builtin_amdgcn_mfma_f32_16x16x32_bf16(
                            a[mt], pb[nt], o[mt][nt], 0, 0, 0);
                __builtin_amdgcn_s_setprio(0);
            }
        }
        for (int nt = 0; nt < 2; nt++) {
            rsum[nt] += __shfl_xor(rsum[nt], 16);
            rsum[nt] += __shfl_xor(rsum[nt], 32);
            lrow[nt] = lrow[nt] * alpha[nt] + rsum[nt];
        }
        __syncthreads();
    }

    // epilogue: ctx[b, s, h*64+d] = O^T[d][q] / l[q]   (8B packed stores)
    for (int nt = 0; nt < 2; nt++) {
        float inv = 1.f / lrow[nt];
        int s = s0 + wq + nt * 16 + l15;
        size_t base = ((size_t)(b * S_SZ + s)) * E_SZ + h * HD_SZ;
        for (int mt = 0; mt < 4; mt++) {
            int d = mt * 16 + quad * 4;
            uint2a w = (uint2a){pk_bf16(o[mt][nt][0] * inv, o[mt][nt][1] * inv),
                                pk_bf16(o[mt][nt][2] * inv, o[mt][nt][3] * inv)};
            *(uint2a*)&ctx[base + d] = w;
        }
    }
}

extern "C" void kernel_launch(void* const* d_in, const int* in_sizes, int n_in,
                              void* d_out, int out_size, void* d_ws, size_t ws_size,
                              hipStream_t stream) {
    const float* q_in = (const float*)d_in[0];
    const float* k_in = (const float*)d_in[1];
    const float* v_in = (const float*)d_in[2];
    const float* Wq = (const float*)d_in[3];
    const float* bq = (const float*)d_in[4];
    const float* Wk = (const float*)d_in[5];
    const float* bk = (const float*)d_in[6];
    const float* Wv = (const float*)d_in[7];
    const float* bv = (const float*)d_in[8];
    const float* Wo = (const float*)d_in[9];
    const float* bo = (const float*)d_in[10];

    ushort_t* ws = (ushort_t*)d_ws;
    const size_t WMAT = (size_t)E_SZ * E_SZ;           // 1M elements
    const size_t TEN = (size_t)B_SZ * S_SZ * E_SZ;     // 8M elements
    ushort_t* Wt = ws;                 // 4 transposed bf16 weights (8 MB)
    ushort_t* qb = ws + 4 * WMAT;      // bf16 copies of inputs
    ushort_t* kb = qb + TEN;
    ushort_t* vb = kb + TEN;
    ushort_t* qp = vb + TEN;           // projected Q/K/V
    ushort_t* kp = qp + TEN;
    ushort_t* vp = kp + TEN;           // stored [B, E, S]
    ushort_t* cx = qb;                 // ctx aliases qb (dead after proj3)

    transpose4<<<dim3(32, 32, 4), dim3(32, 8), 0, stream>>>(Wq, Wk, Wv, Wo, Wt);
    cvt3<<<dim3(4096, 3), 256, 0, stream>>>(q_in, k_in, v_in, qb, kb, vb);
    proj3<<<dim3(8, 64, 3), 256, 0, stream>>>(qb, kb, vb, Wt, bq, bk, bv, qp, kp, vp);
    attn<<<dim3(16, 64), 256, 0, stream>>>(qp, kp, vp, cx);
    gemm_out<<<dim3(8, 64), 256, 0, stream>>>(cx, Wt + 3 * WMAT, bo, (float*)d_out);
}